// Round 5
// baseline (240.784 us; speedup 1.0000x reference)
//
#include <hip/hip_runtime.h>
#include <hip/hip_bf16.h>

typedef __bf16 bf16x8_t __attribute__((ext_vector_type(8)));
typedef float f32x4_t __attribute__((ext_vector_type(4)));

#define SCALE_ZB 7.2134752044448169f   // 5 * log2(e): logits in log2 domain
#define LN2 0.69314718055994531f
#define E2(x) __builtin_amdgcn_exp2f(x)
#define LG2(x) __builtin_amdgcn_logf(x)

// ws byte offsets
#define WS_ACC   0u        // 5 floats used
#define WS_CNT   256u      // int[2048]
#define WS_BASE  8448u     // int[2048]
#define WS_CUR   16640u    // int[2048]
#define WS_PERM  24832u    // int[65536]
#define WS_ANC   294912u   // bf16[262144] in B-fragment order (512 KB)
#define WS_PART  819200u   // float2[65536*2]: per-row (m,s) per M-half (1 MB)
#define WS_ZERO  24832u
// acc: 0 posdot_raw, 1 zsq, 2 hsq, 3 l2se_sum, 4 cent_ssq_over_n

// ---- anchors f32 -> bf16 packed in MFMA B-fragment order + label histogram ----
// layout: [chunk c 0..127][kk 0..3][lane 0..63][e 0..7]
// lane=(g<<4)|l15 holds anchor (c*16+l15), k = kk*32 + g*8 + e
__global__ void prepHist(const float* __restrict__ anc, __bf16* __restrict__ out,
                         const int* __restrict__ labels, int* __restrict__ cnt) {
    int i = blockIdx.x * 256 + threadIdx.x;   // 0..65535
    atomicAdd(&cnt[labels[i]], 1);
    if (i < 32768) {
        int m = i >> 4, k0 = (i & 15) << 3;
        int kk = k0 >> 5, g = (k0 >> 3) & 3, l15 = m & 15, c = m >> 4;
        int lane = (g << 4) | l15;
        int base = (((c << 2) + kk) << 9) + (lane << 3);
        const float4* a4 = (const float4*)anc + (size_t)m * 32 + (k0 >> 2);
        float4 f0 = a4[0], f1 = a4[1];
        bf16x8_t pk;
        pk[0] = (__bf16)f0.x; pk[1] = (__bf16)f0.y; pk[2] = (__bf16)f0.z; pk[3] = (__bf16)f0.w;
        pk[4] = (__bf16)f1.x; pk[5] = (__bf16)f1.y; pk[6] = (__bf16)f1.z; pk[7] = (__bf16)f1.w;
        *(bf16x8_t*)&out[base] = pk;
    }
}

__global__ void scanK(const int* __restrict__ cnt, int* __restrict__ base,
                      int* __restrict__ cursor) {
    __shared__ int wsum[4];
    int t = threadIdx.x, lane = t & 63, w = t >> 6;
    int c[8], tot = 0;
    #pragma unroll
    for (int q = 0; q < 8; ++q) { c[q] = cnt[t * 8 + q]; tot += c[q]; }
    int sc = tot;
    #pragma unroll
    for (int off = 1; off < 64; off <<= 1) {
        int o = __shfl_up(sc, off);
        if (lane >= off) sc += o;
    }
    if (lane == 63) wsum[w] = sc;
    __syncthreads();
    int woff = 0;
    for (int ww = 0; ww < w; ++ww) woff += wsum[ww];
    int ex = woff + sc - tot;
    #pragma unroll
    for (int q = 0; q < 8; ++q) {
        base[t * 8 + q] = ex;
        cursor[t * 8 + q] = ex;
        ex += c[q];
    }
}

__global__ void scatK(const int* __restrict__ labels, int* __restrict__ cursor,
                      int* __restrict__ perm) {
    int i = blockIdx.x * 256 + threadIdx.x;
    int l = labels[i];
    int p = atomicAdd(&cursor[l], 1);
    perm[p] = i;
}

// 4 independent waves per WG (no barriers, no LDS).
// global wave gw = bid*4+w: row-group rg = gw>>1 (32 rows), M-half = gw&1 (1024 anchors).
__launch_bounds__(256, 4)
__global__ void fusedM(const float* __restrict__ z,
                       const float* __restrict__ he,
                       const float* __restrict__ hc,
                       const float* __restrict__ ancf,
                       const int* __restrict__ labels,
                       const __bf16* __restrict__ ancb,
                       float* __restrict__ acc,
                       float2* __restrict__ part) {
    const int tid  = threadIdx.x;
    const int lane = tid & 63;
    const int w    = tid >> 6;
    const int gw   = (blockIdx.x << 2) + w;
    const int rg   = gw >> 1;
    const int half = gw & 1;
    const int l15  = lane & 15, g = lane >> 4;
    const int R0   = rg << 5;

    // ---- h-align slice (grid-stride float4 over all 262144 threads) ----
    float hp = 0.f;
    {
        int gt = (blockIdx.x << 8) + tid;          // 0..262143
        const float4* hev = (const float4*)he;
        const float4* hcv = (const float4*)hc;
        #pragma unroll 4
        for (int i = 0; i < 16; ++i) {
            float4 e = hev[(size_t)i * 262144 + gt];
            float4 c = hcv[(size_t)i * 262144 + gt];
            float dx = e.x - c.x, dy = e.y - c.y, dz = e.z - c.z, dw = e.w - c.w;
            hp += dx * dx + dy * dy + dz * dz + dw * dw;
        }
    }

    // ---- A-fragments from z; half0 computes pos-dot, half1 computes zsq ----
    bf16x8_t Af[2][4];
    float posp = 0.f, zsqp = 0.f;
    #pragma unroll
    for (int rf = 0; rf < 2; ++rf) {
        int row = R0 + (rf << 4) + l15;
        const float4* zr = (const float4*)z + ((size_t)row << 5);
        const float4* ar;
        if (half == 0) {
            int lb = labels[row];
            ar = (const float4*)ancf + ((size_t)lb << 5);
        }
        #pragma unroll
        for (int kk = 0; kk < 4; ++kk) {
            int q = (kk << 3) + (g << 1);
            float4 z0 = zr[q], z1 = zr[q + 1];
            if (half == 0) {
                float4 a0 = ar[q], a1 = ar[q + 1];
                posp += z0.x*a0.x + z0.y*a0.y + z0.z*a0.z + z0.w*a0.w
                      + z1.x*a1.x + z1.y*a1.y + z1.z*a1.z + z1.w*a1.w;
            } else {
                zsqp += z0.x*z0.x + z0.y*z0.y + z0.z*z0.z + z0.w*z0.w
                      + z1.x*z1.x + z1.y*z1.y + z1.z*z1.z + z1.w*z1.w;
            }
            bf16x8_t pk;
            pk[0] = (__bf16)(z0.x * SCALE_ZB); pk[1] = (__bf16)(z0.y * SCALE_ZB);
            pk[2] = (__bf16)(z0.z * SCALE_ZB); pk[3] = (__bf16)(z0.w * SCALE_ZB);
            pk[4] = (__bf16)(z1.x * SCALE_ZB); pk[5] = (__bf16)(z1.y * SCALE_ZB);
            pk[6] = (__bf16)(z1.z * SCALE_ZB); pk[7] = (__bf16)(z1.w * SCALE_ZB);
            Af[rf][kk] = pk;
        }
    }

    // scalar partials -> atomics
    float sp = (half == 0) ? posp : zsqp;
    #pragma unroll
    for (int off = 32; off; off >>= 1) {
        sp += __shfl_xor(sp, off);
        hp += __shfl_xor(hp, off);
    }
    if (lane == 0) {
        atomicAdd(&acc[2], hp);
        atomicAdd(half == 0 ? &acc[0] : &acc[1], sp);
    }

    // ---- main loop: 64 chunks of 16 anchors (this wave's M-half) ----
    float m0[4], s0[4], m1[4], s1[4];
    #pragma unroll
    for (int r = 0; r < 4; ++r) { m0[r] = -1.0e30f; s0[r] = 0.f; m1[r] = -1.0e30f; s1[r] = 0.f; }

    const bf16x8_t* Bp = (const bf16x8_t*)ancb + (half << 14);
    bf16x8_t Bc[4];
    #pragma unroll
    for (int kk = 0; kk < 4; ++kk) Bc[kk] = Bp[(kk << 6) + lane];

    for (int c = 0; c < 64; c += 2) {
        bf16x8_t Bn[4];
        #pragma unroll
        for (int kk = 0; kk < 4; ++kk)
            Bn[kk] = Bp[((((c + 1) << 2) | kk) << 6) + lane];

        f32x4_t aA = {0.f,0.f,0.f,0.f}, aB = {0.f,0.f,0.f,0.f};
        #pragma unroll
        for (int kk = 0; kk < 4; ++kk) {
            aA = __builtin_amdgcn_mfma_f32_16x16x32_bf16(Af[0][kk], Bc[kk], aA, 0, 0, 0);
            aB = __builtin_amdgcn_mfma_f32_16x16x32_bf16(Af[1][kk], Bc[kk], aB, 0, 0, 0);
        }
        if (c + 2 < 64) {
            #pragma unroll
            for (int kk = 0; kk < 4; ++kk)
                Bc[kk] = Bp[((((c + 2) << 2) | kk) << 6) + lane];
        }
        f32x4_t bA = {0.f,0.f,0.f,0.f}, bB = {0.f,0.f,0.f,0.f};
        #pragma unroll
        for (int kk = 0; kk < 4; ++kk) {
            bA = __builtin_amdgcn_mfma_f32_16x16x32_bf16(Af[0][kk], Bn[kk], bA, 0, 0, 0);
            bB = __builtin_amdgcn_mfma_f32_16x16x32_bf16(Af[1][kk], Bn[kk], bB, 0, 0, 0);
        }

        // batched-2 online-LSE update: 3 exp2 per 2 logits
        #pragma unroll
        for (int r = 0; r < 4; ++r) {
            {
                float v0 = aA[r], v1 = bA[r];
                float nm = fmaxf(fmaxf(v0, v1), m0[r]);
                s0[r] = s0[r] * E2(m0[r] - nm) + E2(v0 - nm) + E2(v1 - nm);
                m0[r] = nm;
            }
            {
                float v0 = aB[r], v1 = bB[r];
                float nm = fmaxf(fmaxf(v0, v1), m1[r]);
                s1[r] = s1[r] * E2(m1[r] - nm) + E2(v0 - nm) + E2(v1 - nm);
                m1[r] = nm;
            }
        }
    }

    // ---- merge (m,s) across the 16 anchor-lanes; write per-row partials ----
    #pragma unroll
    for (int r = 0; r < 4; ++r) {
        #pragma unroll
        for (int off = 1; off < 16; off <<= 1) {
            float om = __shfl_xor(m0[r], off), os = __shfl_xor(s0[r], off);
            float nm = fmaxf(m0[r], om);
            s0[r] = s0[r] * E2(m0[r] - nm) + os * E2(om - nm);
            m0[r] = nm;
            om = __shfl_xor(m1[r], off); os = __shfl_xor(s1[r], off);
            nm = fmaxf(m1[r], om);
            s1[r] = s1[r] * E2(m1[r] - nm) + os * E2(om - nm);
            m1[r] = nm;
        }
    }
    if (l15 == 0) {
        #pragma unroll
        for (int r = 0; r < 4; ++r) {
            int row0 = R0 + (g << 2) + r;
            part[(row0 << 1) + half]        = make_float2(m0[r], s0[r]);
            part[((row0 + 16) << 1) + half] = make_float2(m1[r], s1[r]);
        }
    }
}

// ---- merge the two M-half partials per row, LSE, sum ----
__global__ void mergeL(const float4* __restrict__ part4, float* __restrict__ acc) {
    int t = blockIdx.x * 256 + threadIdx.x;   // 0..65535
    float4 p = part4[t];                       // m0,s0,m1,s1
    float nm = fmaxf(p.x, p.z);
    float s = p.y * E2(p.x - nm) + p.w * E2(p.z - nm);
    float lse = nm + LG2(s);
    #pragma unroll
    for (int off = 32; off; off >>= 1) lse += __shfl_xor(lse, off);
    if ((threadIdx.x & 63) == 0) atomicAdd(&acc[3], lse);
}

// ---- centroid: one wave per label, register accumulation ----
__launch_bounds__(64)
__global__ void centW(const float* __restrict__ z,
                      const int* __restrict__ cnt,
                      const int* __restrict__ base,
                      const int* __restrict__ perm,
                      float* __restrict__ acc) {
    const int lane = threadIdx.x;
    const int lb = blockIdx.x;
    const int n = cnt[lb], bs = base[lb];
    float ax = 0.f, ay = 0.f;
    const float2* z2 = (const float2*)z;
    for (int e0 = 0; e0 < n; e0 += 64) {
        int pe = (e0 + lane < n) ? perm[bs + e0 + lane] : 0;
        int c2 = n - e0; if (c2 > 64) c2 = 64;
        int j = 0;
        for (; j + 3 < c2; j += 4) {
            int r0 = __shfl(pe, j), r1 = __shfl(pe, j + 1);
            int r2 = __shfl(pe, j + 2), r3 = __shfl(pe, j + 3);
            float2 v0 = z2[((size_t)r0 << 6) + lane];
            float2 v1 = z2[((size_t)r1 << 6) + lane];
            float2 v2 = z2[((size_t)r2 << 6) + lane];
            float2 v3 = z2[((size_t)r3 << 6) + lane];
            ax += v0.x + v1.x + v2.x + v3.x;
            ay += v0.y + v1.y + v2.y + v3.y;
        }
        for (; j < c2; ++j) {
            int r0 = __shfl(pe, j);
            float2 v0 = z2[((size_t)r0 << 6) + lane];
            ax += v0.x; ay += v0.y;
        }
    }
    float ssq = ax * ax + ay * ay;
    #pragma unroll
    for (int off = 32; off; off >>= 1) ssq += __shfl_xor(ssq, off);
    if (lane == 0) atomicAdd(&acc[4], ssq / fmaxf((float)n, 1.f));
}

__global__ void finalize(const float* __restrict__ acc, float* __restrict__ out) {
    float lc   = (LN2 * acc[3] - 5.0f * acc[0]) * (1.0f / 65536.0f);
    float cent = (acc[1] - acc[4]) * (1.0f / 8388608.0f);
    float hal  = acc[2] * (1.0f / 16777216.0f);
    out[0] = lc + 0.05f * cent + 0.1f * hal;
}

extern "C" void kernel_launch(void* const* d_in, const int* in_sizes, int n_in,
                              void* d_out, int out_size, void* d_ws, size_t ws_size,
                              hipStream_t stream) {
    const float* z      = (const float*)d_in[0];
    const float* he     = (const float*)d_in[1];
    const float* hc     = (const float*)d_in[2];
    const float* anc    = (const float*)d_in[3];
    const int*   labels = (const int*)d_in[4];

    char* ws = (char*)d_ws;
    float*  acc    = (float*)(ws + WS_ACC);
    int*    cnt    = (int*)(ws + WS_CNT);
    int*    basep  = (int*)(ws + WS_BASE);
    int*    cursor = (int*)(ws + WS_CUR);
    int*    perm   = (int*)(ws + WS_PERM);
    __bf16* ancb   = (__bf16*)(ws + WS_ANC);
    float2* part   = (float2*)(ws + WS_PART);

    hipMemsetAsync(d_ws, 0, WS_ZERO, stream);
    prepHist<<<256, 256, 0, stream>>>(anc, ancb, labels, cnt);
    scanK<<<1, 256, 0, stream>>>(cnt, basep, cursor);
    scatK<<<256, 256, 0, stream>>>(labels, cursor, perm);
    fusedM<<<1024, 256, 0, stream>>>(z, he, hc, anc, labels, ancb, acc, part);
    mergeL<<<256, 256, 0, stream>>>((const float4*)part, acc);
    centW<<<2048, 64, 0, stream>>>(z, cnt, basep, perm, acc);
    finalize<<<1, 1, 0, stream>>>(acc, (float*)d_out);
}